// Round 16
// baseline (365.378 us; speedup 1.0000x reference)
//
#include <hip/hip_runtime.h>
#include <cmath>

typedef short short8 __attribute__((ext_vector_type(8)));
typedef unsigned short u16x8 __attribute__((ext_vector_type(8)));
typedef float f32x4 __attribute__((ext_vector_type(4)));

struct EncParams { float scale[10]; int res[10]; };

__device__ __forceinline__ unsigned short f2bf(float f) {
  unsigned u = __builtin_bit_cast(unsigned, f);
  return (unsigned short)((u + 0x7FFFu + ((u >> 16) & 1u)) >> 16);  // RNE
}

// ---------------- hashgrid level encode (serial, proven R5/R9/R11 form) ----------------
__device__ __forceinline__ void enc_level(float x, float y, float sc, int res,
    const float* __restrict__ table, int l, unsigned short* er) {
  float posx = __fadd_rn(__fmul_rn(x, sc), 0.5f);
  float posy = __fadd_rn(__fmul_rn(y, sc), 0.5f);
  float gx = floorf(posx), gy = floorf(posy);
  float fx = posx - gx, fy = posy - gy;
  unsigned px = (unsigned)gx, py = (unsigned)gy;
  unsigned idx[4];
  if (res * res <= (1 << 20)) {      // dense: row-major x + y*res
    unsigned b = px + py * (unsigned)res;
    idx[0] = b; idx[1] = b + 1u;
    idx[2] = b + (unsigned)res; idx[3] = b + (unsigned)res + 1u;
  } else {                           // spatial hash (level 9 only)
    unsigned hy0 = py * 2654435761u;
    unsigned hy1 = hy0 + 2654435761u;          // (py+1)*prime mod 2^32
    idx[0] = (px ^ hy0) & 0xFFFFFu;
    idx[1] = ((px + 1u) ^ hy0) & 0xFFFFFu;
    idx[2] = (px ^ hy1) & 0xFFFFFu;
    idx[3] = ((px + 1u) ^ hy1) & 0xFFFFFu;
  }
  float omx = 1.0f - fx, omy = 1.0f - fy;
  float w[4] = { omx * omy, fx * omy, omx * fy, fx * fy };
  const float4* tl = reinterpret_cast<const float4*>(table) + ((size_t)l << 21);
  float acc[8] = {0.f,0.f,0.f,0.f,0.f,0.f,0.f,0.f};
#pragma unroll
  for (int c = 0; c < 4; ++c) {
    float4 lo = tl[2 * (size_t)idx[c]];
    float4 hi = tl[2 * (size_t)idx[c] + 1];
    float wc = w[c];
    acc[0] = fmaf(wc, lo.x, acc[0]); acc[1] = fmaf(wc, lo.y, acc[1]);
    acc[2] = fmaf(wc, lo.z, acc[2]); acc[3] = fmaf(wc, lo.w, acc[3]);
    acc[4] = fmaf(wc, hi.x, acc[4]); acc[5] = fmaf(wc, hi.y, acc[5]);
    acc[6] = fmaf(wc, hi.z, acc[6]); acc[7] = fmaf(wc, hi.w, acc[7]);
  }
  u16x8 o;
#pragma unroll
  for (int j = 0; j < 8; ++j) o[j] = f2bf(acc[j]);
  *reinterpret_cast<u16x8*>(er + 8 * l) = o;
}

// ---------------- fused encode + MLP (BM=64, 512 thr, 2 blocks/CU) ----------------
// FROZEN: mfma operand order (act arg0, W arg1), scalar epilogues, no d_ws,
// separate encS/hS, serial enc_level. R12/R13/R14/R15 all showed: this
// compiler caps at 128 VGPR; any added live state spills. So occupancy comes
// from LDS instead: BM=64 halves LDS to 62KB -> 2 blocks/CU -> 4 waves/SIMD
// (2x R11) with a SMALLER per-wave register footprint (acc 48 vs 96).
// Per-output arithmetic bit-identical to R5/R9/R11.
__global__ __launch_bounds__(512, 2) void nf_main(
    const float* __restrict__ coords, const float* __restrict__ table,
    const float* __restrict__ w1, const float* __restrict__ w2,
    const float* __restrict__ b1v, const float* __restrict__ b2v,
    float* __restrict__ out, EncParams P) {
  __shared__ __align__(16) unsigned short encS[64][104];  // 13,312 B
  __shared__ __align__(16) unsigned short hS[64][392];    // 50,176 B  (total 62 KB)
  const int tid = threadIdx.x;
  const size_t rowBase = (size_t)blockIdx.x * 64;
  const int lane = tid & 63, wv = tid >> 6;      // 8 waves
  const int lr = lane & 15, lhi = lane >> 4;

  // ---- encode phase: 8 threads per point, <=2 levels each ----
  {
    const int p = tid & 63, g = tid >> 6;
    float2 c = reinterpret_cast<const float2*>(coords)[rowBase + p];
    unsigned short* er = &encS[p][0];
    if (g == 0) {
      enc_level(c.x, c.y, P.scale[0], P.res[0], table, 0, er);
      enc_level(c.x, c.y, P.scale[8], P.res[8], table, 8, er);
    } else if (g == 1) {
      enc_level(c.x, c.y, P.scale[1], P.res[1], table, 1, er);
      enc_level(c.x, c.y, P.scale[9], P.res[9], table, 9, er);
    } else if (g == 2) {
      enc_level(c.x, c.y, P.scale[2], P.res[2], table, 2, er);
      enc_level(c.x, c.y, P.scale[6], P.res[6], table, 6, er);
    } else if (g == 3) {
      enc_level(c.x, c.y, P.scale[3], P.res[3], table, 3, er);
      enc_level(c.x, c.y, P.scale[7], P.res[7], table, 7, er);
    } else if (g == 4) {
      enc_level(c.x, c.y, P.scale[4], P.res[4], table, 4, er);
    } else if (g == 5) {
      enc_level(c.x, c.y, P.scale[5], P.res[5], table, 5, er);
    } else if (g == 6) {
      u16x8 z = {};
      *reinterpret_cast<u16x8*>(er + 80) = z;   // zero pad k=80..87
    } else {
      u16x8 z = {};
      *reinterpret_cast<u16x8*>(er + 88) = z;   // zero pad k=88..95
    }
  }
  __syncthreads();

  // ---- layer 1: [64x96] x [96 x (48 per wave)] (ri=4, cf=3) ----
  {
    f32x4 acc1[4][3];
#pragma unroll
    for (int ri = 0; ri < 4; ++ri)
#pragma unroll
      for (int cf = 0; cf < 3; ++cf) acc1[ri][cf] = (f32x4){0.f, 0.f, 0.f, 0.f};
#pragma unroll
    for (int ks = 0; ks < 3; ++ks) {
      short8 a[4];
#pragma unroll
      for (int ri = 0; ri < 4; ++ri)
        a[ri] = *reinterpret_cast<const short8*>(&encS[16 * ri + lr][32 * ks + 8 * lhi]);
#pragma unroll
      for (int cf = 0; cf < 3; ++cf) {
        const int colB = 48 * wv + 16 * cf + lr;
        short8 b;
#pragma unroll
        for (int j = 0; j < 8; ++j) {
          int k = 32 * ks + 8 * lhi + j;
          b[j] = (k < 80) ? (short)f2bf(w1[(size_t)k * 384 + colB]) : (short)0;
        }
#pragma unroll
        for (int ri = 0; ri < 4; ++ri)
          acc1[ri][cf] = __builtin_amdgcn_mfma_f32_16x16x32_bf16(a[ri], b, acc1[ri][cf], 0, 0, 0);
      }
    }
#pragma unroll
    for (int ri = 0; ri < 4; ++ri)
#pragma unroll
      for (int cf = 0; cf < 3; ++cf) {
        int col = 48 * wv + 16 * cf + lr;
        float bb = b1v[col];
#pragma unroll
        for (int j = 0; j < 4; ++j) {
          int r = 16 * ri + 4 * lhi + j;
          float v = acc1[ri][cf][j] + bb;
          hS[r][col] = f2bf(fmaxf(v, 0.0f));
        }
      }
  }
  __syncthreads();

  // ---- layer 2: [64x384] x [384 x (96 per wave)] in 2 chunks of 48 cols ----
#pragma unroll
  for (int cc = 0; cc < 2; ++cc) {
    f32x4 acc[4][3];
#pragma unroll
    for (int ri = 0; ri < 4; ++ri)
#pragma unroll
      for (int cf = 0; cf < 3; ++cf) acc[ri][cf] = (f32x4){0.f, 0.f, 0.f, 0.f};
#pragma unroll
    for (int ks = 0; ks < 12; ++ks) {
      short8 a[4];
#pragma unroll
      for (int ri = 0; ri < 4; ++ri)
        a[ri] = *reinterpret_cast<const short8*>(&hS[16 * ri + lr][32 * ks + 8 * lhi]);
#pragma unroll
      for (int cf = 0; cf < 3; ++cf) {
        const int colB = 96 * wv + 48 * cc + 16 * cf + lr;
        short8 b;
#pragma unroll
        for (int j = 0; j < 8; ++j) {
          int k = 32 * ks + 8 * lhi + j;
          b[j] = (short)f2bf(w2[(size_t)k * 768 + colB]);
        }
#pragma unroll
        for (int ri = 0; ri < 4; ++ri)
          acc[ri][cf] = __builtin_amdgcn_mfma_f32_16x16x32_bf16(a[ri], b, acc[ri][cf], 0, 0, 0);
      }
    }
#pragma unroll
    for (int ri = 0; ri < 4; ++ri)
#pragma unroll
      for (int cf = 0; cf < 3; ++cf) {
        int col = 96 * wv + 48 * cc + 16 * cf + lr;
        float bb = b2v[col];
#pragma unroll
        for (int j = 0; j < 4; ++j) {
          int r = 16 * ri + 4 * lhi + j;
          out[(rowBase + r) * 768 + col] = acc[ri][cf][j] + bb;
        }
      }
  }
}

extern "C" void kernel_launch(void* const* d_in, const int* in_sizes, int n_in,
                              void* d_out, int out_size, void* d_ws, size_t ws_size,
                              hipStream_t stream) {
  const float* coords = (const float*)d_in[0];
  const float* table  = (const float*)d_in[1];
  const float* w1     = (const float*)d_in[2];
  const float* b1     = (const float*)d_in[3];
  const float* w2     = (const float*)d_in[4];
  const float* b2     = (const float*)d_in[5];
  float* out = (float*)d_out;

  EncParams P;
  double pls = exp((log(1024.0) - log(16.0)) / 9.0);
  static const int RES[10] = {16, 26, 41, 65, 102, 162, 257, 407, 646, 1025};
  for (int l = 0; l < 10; ++l) {
    double sc = 16.0 * pow(pls, (double)l) - 1.0;
    P.scale[l] = (float)sc;
    P.res[l] = RES[l];
  }

  // FROZEN FAMILY (no d_ws, no swap, no union, serial encode, 512-thr blocks,
  // no software prefetch — three attempts all spilled at the 128-VGPR cap).
  // Occupancy via LDS: BM=64 -> 62KB -> 2 blocks/CU -> 4 waves/SIMD.
  nf_main<<<2048, 512, 0, stream>>>(coords, table, w1, w2, b1, b2, out, P);
}

// Round 17
// 282.923 us; speedup vs baseline: 1.2914x; 1.2914x over previous
//
#include <hip/hip_runtime.h>
#include <cmath>

typedef short short8 __attribute__((ext_vector_type(8)));
typedef unsigned short u16x8 __attribute__((ext_vector_type(8)));
typedef float f32x4 __attribute__((ext_vector_type(4)));

struct EncParams { float scale[10]; int res[10]; };

__device__ __forceinline__ unsigned short f2bf(float f) {
  unsigned u = __builtin_bit_cast(unsigned, f);
  return (unsigned short)((u + 0x7FFFu + ((u >> 16) & 1u)) >> 16);  // RNE
}

// ---------------- hashgrid level encode (serial, proven R5/R9/R11 form) ----------------
__device__ __forceinline__ void enc_level(float x, float y, float sc, int res,
    const float* __restrict__ table, int l, unsigned short* er) {
  float posx = __fadd_rn(__fmul_rn(x, sc), 0.5f);
  float posy = __fadd_rn(__fmul_rn(y, sc), 0.5f);
  float gx = floorf(posx), gy = floorf(posy);
  float fx = posx - gx, fy = posy - gy;
  unsigned px = (unsigned)gx, py = (unsigned)gy;
  unsigned idx[4];
  if (res * res <= (1 << 20)) {      // dense: row-major x + y*res
    unsigned b = px + py * (unsigned)res;
    idx[0] = b; idx[1] = b + 1u;
    idx[2] = b + (unsigned)res; idx[3] = b + (unsigned)res + 1u;
  } else {                           // spatial hash (level 9 only)
    unsigned hy0 = py * 2654435761u;
    unsigned hy1 = hy0 + 2654435761u;          // (py+1)*prime mod 2^32
    idx[0] = (px ^ hy0) & 0xFFFFFu;
    idx[1] = ((px + 1u) ^ hy0) & 0xFFFFFu;
    idx[2] = (px ^ hy1) & 0xFFFFFu;
    idx[3] = ((px + 1u) ^ hy1) & 0xFFFFFu;
  }
  float omx = 1.0f - fx, omy = 1.0f - fy;
  float w[4] = { omx * omy, fx * omy, omx * fy, fx * fy };
  const float4* tl = reinterpret_cast<const float4*>(table) + ((size_t)l << 21);
  float acc[8] = {0.f,0.f,0.f,0.f,0.f,0.f,0.f,0.f};
#pragma unroll
  for (int c = 0; c < 4; ++c) {
    float4 lo = tl[2 * (size_t)idx[c]];
    float4 hi = tl[2 * (size_t)idx[c] + 1];
    float wc = w[c];
    acc[0] = fmaf(wc, lo.x, acc[0]); acc[1] = fmaf(wc, lo.y, acc[1]);
    acc[2] = fmaf(wc, lo.z, acc[2]); acc[3] = fmaf(wc, lo.w, acc[3]);
    acc[4] = fmaf(wc, hi.x, acc[4]); acc[5] = fmaf(wc, hi.y, acc[5]);
    acc[6] = fmaf(wc, hi.z, acc[6]); acc[7] = fmaf(wc, hi.w, acc[7]);
  }
  u16x8 o;
#pragma unroll
  for (int j = 0; j < 8; ++j) o[j] = f2bf(acc[j]);
  *reinterpret_cast<u16x8*>(er + 8 * l) = o;
}

// ---------------- fused encode + MLP (R11 structure + W1 hoist) ----------------
// FROZEN: mfma operand order (act arg0, W arg1), scalar epilogues, no d_ws,
// separate encS/hS, serial enc_level, BM=128, 512 threads, grid 1024.
// Constraint map (measured): VGPR cap 128 (R12/R13/R14/R15 spills); 512-thr
// blocks never co-schedule 2/CU (R16); 1024-thr blocks get 64 VGPR (R13/R14).
// ONLY change vs R11: W1 fragment build hoisted ABOVE the encode barrier —
// its 72 L2-latency loads/lane overlap the encode's HBM/L3 gathers, and the
// L1 MFMA phase becomes load-free. 36 VGPR live through encode (~100 peak).
__global__ __launch_bounds__(512, 2) void nf_main(
    const float* __restrict__ coords, const float* __restrict__ table,
    const float* __restrict__ w1, const float* __restrict__ w2,
    const float* __restrict__ b1v, const float* __restrict__ b2v,
    float* __restrict__ out, EncParams P) {
  __shared__ __align__(16) unsigned short encS[128][104];  // 26,624 B
  __shared__ __align__(16) unsigned short hS[128][392];    // 100,352 B
  const int tid = threadIdx.x;
  const size_t rowBase = (size_t)blockIdx.x * 128;
  const int lane = tid & 63, wv = tid >> 6;      // 8 waves
  const int lr = lane & 15, lhi = lane >> 4;

  // ---- W1 fragments first: LDS-independent, overlap with encode gathers ----
  short8 bW1[3][3];
#pragma unroll
  for (int ks = 0; ks < 3; ++ks)
#pragma unroll
    for (int cf = 0; cf < 3; ++cf) {
      const int colB = 48 * wv + 16 * cf + lr;
#pragma unroll
      for (int j = 0; j < 8; ++j) {
        int k = 32 * ks + 8 * lhi + j;
        bW1[ks][cf][j] = (k < 80) ? (short)f2bf(w1[(size_t)k * 384 + colB]) : (short)0;
      }
    }

  // ---- encode phase: 4 threads per point, disjoint level sets ----
  {
    const int p = tid & 127, g = tid >> 7;
    float2 c = reinterpret_cast<const float2*>(coords)[rowBase + p];
    unsigned short* er = &encS[p][0];
    if (g == 0) {
      enc_level(c.x, c.y, P.scale[0], P.res[0], table, 0, er);
      enc_level(c.x, c.y, P.scale[4], P.res[4], table, 4, er);
      enc_level(c.x, c.y, P.scale[8], P.res[8], table, 8, er);
    } else if (g == 1) {
      enc_level(c.x, c.y, P.scale[1], P.res[1], table, 1, er);
      enc_level(c.x, c.y, P.scale[5], P.res[5], table, 5, er);
      enc_level(c.x, c.y, P.scale[9], P.res[9], table, 9, er);
    } else if (g == 2) {
      enc_level(c.x, c.y, P.scale[2], P.res[2], table, 2, er);
      enc_level(c.x, c.y, P.scale[6], P.res[6], table, 6, er);
      u16x8 z = {};
      *reinterpret_cast<u16x8*>(er + 80) = z;   // zero pad k=80..87
    } else {
      enc_level(c.x, c.y, P.scale[3], P.res[3], table, 3, er);
      enc_level(c.x, c.y, P.scale[7], P.res[7], table, 7, er);
      u16x8 z = {};
      *reinterpret_cast<u16x8*>(er + 88) = z;   // zero pad k=88..95
    }
  }
  __syncthreads();

  // ---- layer 1: [128x96] x [96 x (48 per wave)] — load-free (bW1 in regs) ----
  f32x4 acc1[8][3];
#pragma unroll
  for (int ri = 0; ri < 8; ++ri)
#pragma unroll
    for (int cf = 0; cf < 3; ++cf) acc1[ri][cf] = (f32x4){0.f, 0.f, 0.f, 0.f};
#pragma unroll
  for (int ks = 0; ks < 3; ++ks) {
    short8 a[8];
#pragma unroll
    for (int ri = 0; ri < 8; ++ri)
      a[ri] = *reinterpret_cast<const short8*>(&encS[16 * ri + lr][32 * ks + 8 * lhi]);
#pragma unroll
    for (int cf = 0; cf < 3; ++cf)
#pragma unroll
      for (int ri = 0; ri < 8; ++ri)
        acc1[ri][cf] = __builtin_amdgcn_mfma_f32_16x16x32_bf16(a[ri], bW1[ks][cf], acc1[ri][cf], 0, 0, 0);
  }
#pragma unroll
  for (int ri = 0; ri < 8; ++ri)
#pragma unroll
    for (int cf = 0; cf < 3; ++cf) {
      int col = 48 * wv + 16 * cf + lr;
      float bb = b1v[col];
#pragma unroll
      for (int j = 0; j < 4; ++j) {
        int r = 16 * ri + 4 * lhi + j;
        float v = acc1[ri][cf][j] + bb;
        hS[r][col] = f2bf(fmaxf(v, 0.0f));
      }
    }
  __syncthreads();

  // ---- layer 2: [128x384] x [384 x (96 per wave)] in 2 chunks of 48 cols ----
#pragma unroll
  for (int cc = 0; cc < 2; ++cc) {
    f32x4 acc[8][3];
#pragma unroll
    for (int ri = 0; ri < 8; ++ri)
#pragma unroll
      for (int cf = 0; cf < 3; ++cf) acc[ri][cf] = (f32x4){0.f, 0.f, 0.f, 0.f};
#pragma unroll
    for (int ks = 0; ks < 12; ++ks) {
      short8 a[8];
#pragma unroll
      for (int ri = 0; ri < 8; ++ri)
        a[ri] = *reinterpret_cast<const short8*>(&hS[16 * ri + lr][32 * ks + 8 * lhi]);
#pragma unroll
      for (int cf = 0; cf < 3; ++cf) {
        const int colB = 96 * wv + 48 * cc + 16 * cf + lr;
        short8 b;
#pragma unroll
        for (int j = 0; j < 8; ++j) {
          int k = 32 * ks + 8 * lhi + j;
          b[j] = (short)f2bf(w2[(size_t)k * 768 + colB]);
        }
#pragma unroll
        for (int ri = 0; ri < 8; ++ri)
          acc[ri][cf] = __builtin_amdgcn_mfma_f32_16x16x32_bf16(a[ri], b, acc[ri][cf], 0, 0, 0);
      }
    }
#pragma unroll
    for (int ri = 0; ri < 8; ++ri)
#pragma unroll
      for (int cf = 0; cf < 3; ++cf) {
        int col = 96 * wv + 48 * cc + 16 * cf + lr;
        float bb = b2v[col];
#pragma unroll
        for (int j = 0; j < 4; ++j) {
          int r = 16 * ri + 4 * lhi + j;
          out[(rowBase + r) * 768 + col] = acc[ri][cf][j] + bb;
        }
      }
  }
}

extern "C" void kernel_launch(void* const* d_in, const int* in_sizes, int n_in,
                              void* d_out, int out_size, void* d_ws, size_t ws_size,
                              hipStream_t stream) {
  const float* coords = (const float*)d_in[0];
  const float* table  = (const float*)d_in[1];
  const float* w1     = (const float*)d_in[2];
  const float* b1     = (const float*)d_in[3];
  const float* w2     = (const float*)d_in[4];
  const float* b2     = (const float*)d_in[5];
  float* out = (float*)d_out;

  EncParams P;
  double pls = exp((log(1024.0) - log(16.0)) / 9.0);
  static const int RES[10] = {16, 26, 41, 65, 102, 162, 257, 407, 646, 1025};
  for (int l = 0; l < 10; ++l) {
    double sc = 16.0 * pow(pls, (double)l) - 1.0;
    P.scale[l] = (float)sc;
    P.res[l] = RES[l];
  }

  // FROZEN FAMILY. Best verified config (R11) + W1-hoist only.
  nf_main<<<1024, 512, 0, stream>>>(coords, table, w1, w2, b1, b2, out, P);
}